// Round 2
// baseline (252.451 us; speedup 1.0000x reference)
//
#include <hip/hip_runtime.h>

#define N_NODES 10000
#define N_EDGES 640000
#define D 128

// ---------------------------------------------------------------- utilities
__global__ __launch_bounds__(256) void k_zero_i32(int* __restrict__ p, int n) {
    int i = blockIdx.x * 256 + threadIdx.x;
    if (i < n) p[i] = 0;
}

// count in-degree (edges only; self loop accounted as +1 later)
__global__ __launch_bounds__(256) void k_count(const int* __restrict__ col,
                                               int* __restrict__ cnt) {
    int e = blockIdx.x * 256 + threadIdx.x;
    if (e < N_EDGES) atomicAdd(&cnt[col[e]], 1);
}

// single-block exclusive scan of cnt[0..N_NODES) -> offsets, cursor; also dis = rsqrt(cnt+1)
#define SCAN_CH 10  // 1024 * 10 >= 10000
__global__ __launch_bounds__(1024) void k_scan(const int* __restrict__ cnt,
                                               int* __restrict__ offsets,
                                               int* __restrict__ cursor,
                                               float* __restrict__ dis) {
    __shared__ int s[1024];
    int t = threadIdx.x;
    int base_i = t * SCAN_CH;
    int v[SCAN_CH];
    int sum = 0;
#pragma unroll
    for (int u = 0; u < SCAN_CH; ++u) {
        int i = base_i + u;
        int x = (i < N_NODES) ? cnt[i] : 0;
        v[u] = x;
        sum += x;
    }
    s[t] = sum;
    __syncthreads();
    for (int off = 1; off < 1024; off <<= 1) {
        int add = (t >= off) ? s[t - off] : 0;
        __syncthreads();
        s[t] += add;
        __syncthreads();
    }
    int ex = s[t] - sum;  // exclusive prefix of this thread's chunk
#pragma unroll
    for (int u = 0; u < SCAN_CH; ++u) {
        int i = base_i + u;
        if (i < N_NODES) {
            offsets[i] = ex;
            cursor[i]  = ex;
            dis[i] = rsqrtf((float)(v[u] + 1));  // +1 self loop
            ex += v[u];
        }
    }
    if (t == 1023) offsets[N_NODES] = s[1023];
}

// place edges into CSR-by-destination (order within segment is arbitrary)
__global__ __launch_bounds__(256) void k_fill(const int* __restrict__ row,
                                              const int* __restrict__ col,
                                              int* __restrict__ cursor,
                                              int* __restrict__ sorted_row) {
    int e = blockIdx.x * 256 + threadIdx.x;
    if (e < N_EDGES) {
        int c = col[e];
        int p = atomicAdd(&cursor[c], 1);
        sorted_row[p] = row[e];
    }
}

// ---------------------------------------------------------------- GEMM
// h[r][:] = dis[r] * (in[r][:] @ W)   in:[N,128] W:[128,128]
// block (32,8): 32 col-groups (float4), 8 row-groups of 4 rows -> 32 rows/block
#define FMA4(acc, s, w)                    \
    acc.x = fmaf(s, w.x, acc.x);           \
    acc.y = fmaf(s, w.y, acc.y);           \
    acc.z = fmaf(s, w.z, acc.z);           \
    acc.w = fmaf(s, w.w, acc.w);

__global__ __launch_bounds__(256) void k_gemm_scale(const float* __restrict__ in,
                                                    const float* __restrict__ W,
                                                    const float* __restrict__ dis,
                                                    float* __restrict__ h) {
    __shared__ float4 sW[128 * 32];  // 64 KB
    const float4* W4 = (const float4*)W;
    int cx = threadIdx.x;              // 0..31
    int tid = threadIdx.y * 32 + cx;   // 0..255
    for (int i = tid; i < 128 * 32; i += 256) sW[i] = W4[i];
    __syncthreads();

    int r0 = blockIdx.x * 32 + threadIdx.y * 4;  // 4 consecutive rows per thread
    if (r0 >= N_NODES) return;  // N%4==0 so rows are all-or-nothing valid

    const float4* xr = (const float4*)(in + (size_t)r0 * D);  // 32 float4 per row
    float4 acc0 = {0, 0, 0, 0}, acc1 = {0, 0, 0, 0}, acc2 = {0, 0, 0, 0}, acc3 = {0, 0, 0, 0};

#pragma unroll 4
    for (int k4 = 0; k4 < 32; ++k4) {
        float4 a0 = xr[k4];
        float4 a1 = xr[32 + k4];
        float4 a2 = xr[64 + k4];
        float4 a3 = xr[96 + k4];
        float4 w;
        w = sW[(k4 * 4 + 0) * 32 + cx];
        FMA4(acc0, a0.x, w) FMA4(acc1, a1.x, w) FMA4(acc2, a2.x, w) FMA4(acc3, a3.x, w)
        w = sW[(k4 * 4 + 1) * 32 + cx];
        FMA4(acc0, a0.y, w) FMA4(acc1, a1.y, w) FMA4(acc2, a2.y, w) FMA4(acc3, a3.y, w)
        w = sW[(k4 * 4 + 2) * 32 + cx];
        FMA4(acc0, a0.z, w) FMA4(acc1, a1.z, w) FMA4(acc2, a2.z, w) FMA4(acc3, a3.z, w)
        w = sW[(k4 * 4 + 3) * 32 + cx];
        FMA4(acc0, a0.w, w) FMA4(acc1, a1.w, w) FMA4(acc2, a2.w, w) FMA4(acc3, a3.w, w)
    }

    float4* h4 = (float4*)h;
#pragma unroll
    for (int j = 0; j < 4; ++j) {
        float ds = dis[r0 + j];
        float4 a = (j == 0) ? acc0 : (j == 1) ? acc1 : (j == 2) ? acc2 : acc3;
        float4 o;
        o.x = a.x * ds; o.y = a.y * ds; o.z = a.z * ds; o.w = a.w * ds;
        h4[(size_t)(r0 + j) * 32 + cx] = o;
    }
}

// ---------------------------------------------------------------- gather
// out[c][:] = act( dis[c] * (h[c][:] + sum_{e in CSR[c]} h[row_e][:]) + b[:] )
__global__ __launch_bounds__(128) void k_gather(const float* __restrict__ h,
                                                const int* __restrict__ offsets,
                                                const int* __restrict__ sorted_row,
                                                const float* __restrict__ dis,
                                                const float* __restrict__ b,
                                                float* __restrict__ out, int relu) {
    int c = blockIdx.x;
    int t = threadIdx.x;
    float acc = h[(size_t)c * D + t];  // self loop
    int beg = offsets[c], end = offsets[c + 1];
    int j = beg;
    for (; j + 4 <= end; j += 4) {
        int r0 = sorted_row[j];
        int r1 = sorted_row[j + 1];
        int r2 = sorted_row[j + 2];
        int r3 = sorted_row[j + 3];
        float v0 = h[(size_t)r0 * D + t];
        float v1 = h[(size_t)r1 * D + t];
        float v2 = h[(size_t)r2 * D + t];
        float v3 = h[(size_t)r3 * D + t];
        acc += v0; acc += v1; acc += v2; acc += v3;
    }
    for (; j < end; ++j) acc += h[(size_t)sorted_row[j] * D + t];
    float o = dis[c] * acc + b[t];
    if (relu) o = fmaxf(o, 0.0f);
    out[(size_t)c * D + t] = o;
}

// ---------------------------------------------------------------- launch
extern "C" void kernel_launch(void* const* d_in, const int* in_sizes, int n_in,
                              void* d_out, int out_size, void* d_ws, size_t ws_size,
                              hipStream_t stream) {
    const float* x  = (const float*)d_in[0];
    const int*   ei = (const int*)d_in[1];
    const float* W1 = (const float*)d_in[2];
    const float* b1 = (const float*)d_in[3];
    const float* W2 = (const float*)d_in[4];
    const float* b2 = (const float*)d_in[5];

    float* out = (float*)d_out;
    float* x2 = out;                       // first tuple element
    float* x1 = out + (size_t)N_NODES * D; // second tuple element

    const int* row = ei;            // edge_index[0]
    const int* col = ei + N_EDGES;  // edge_index[1]

    // workspace layout (all 16B-aligned chunks)
    int* cnt        = (int*)d_ws;                    // 10000 (use 10016 stride)
    int* offsets    = cnt + 10016;                   // 10001
    int* cursor     = offsets + 10016;               // 10000
    float* dis      = (float*)(cursor + 10016);      // 10000
    int* sorted_row = (int*)(dis + 10016);           // 640000
    float* h        = (float*)(sorted_row + N_EDGES); // 1280000 floats
    // total ~7.9 MB

    k_zero_i32<<<(N_NODES + 255) / 256, 256, 0, stream>>>(cnt, N_NODES);
    k_count<<<(N_EDGES + 255) / 256, 256, 0, stream>>>(col, cnt);
    k_scan<<<1, 1024, 0, stream>>>(cnt, offsets, cursor, dis);
    k_fill<<<(N_EDGES + 255) / 256, 256, 0, stream>>>(row, col, cursor, sorted_row);

    // layer 1
    k_gemm_scale<<<(N_NODES + 31) / 32, dim3(32, 8), 0, stream>>>(x, W1, dis, h);
    k_gather<<<N_NODES, 128, 0, stream>>>(h, offsets, sorted_row, dis, b1, x1, 1);
    // layer 2
    k_gemm_scale<<<(N_NODES + 31) / 32, dim3(32, 8), 0, stream>>>(x1, W2, dis, h);
    k_gather<<<N_NODES, 128, 0, stream>>>(h, offsets, sorted_row, dis, b2, x2, 0);
}

// Round 3
// 224.840 us; speedup vs baseline: 1.1228x; 1.1228x over previous
//
#include <hip/hip_runtime.h>

#define N_NODES 10000
#define N_EDGES 640000
#define D 128

// ---------------------------------------------------------------- helpers
__device__ __forceinline__ float asf(unsigned int u) {
    union { unsigned int i; float f; } v; v.i = u; return v.f;
}
__device__ __forceinline__ unsigned int f2bf(float f) {
    union { float f; unsigned int i; } v; v.f = f;
    return (v.i + 0x7fffu + ((v.i >> 16) & 1u)) >> 16;  // RNE
}

// ---------------------------------------------------------------- utilities
__global__ __launch_bounds__(256) void k_zero_i32(int* __restrict__ p, int n) {
    int i = blockIdx.x * 256 + threadIdx.x;
    if (i < n) p[i] = 0;
}

__global__ __launch_bounds__(256) void k_count(const int* __restrict__ col,
                                               int* __restrict__ cnt) {
    int e = blockIdx.x * 256 + threadIdx.x;
    if (e < N_EDGES) atomicAdd(&cnt[col[e]], 1);
}

// single-block exclusive scan; also dis = rsqrt(cnt+1)
#define SCAN_CH 10
__global__ __launch_bounds__(1024) void k_scan(const int* __restrict__ cnt,
                                               int* __restrict__ offsets,
                                               int* __restrict__ cursor,
                                               float* __restrict__ dis) {
    __shared__ int s[1024];
    int t = threadIdx.x;
    int base_i = t * SCAN_CH;
    int v[SCAN_CH];
    int sum = 0;
#pragma unroll
    for (int u = 0; u < SCAN_CH; ++u) {
        int i = base_i + u;
        int x = (i < N_NODES) ? cnt[i] : 0;
        v[u] = x;
        sum += x;
    }
    s[t] = sum;
    __syncthreads();
    for (int off = 1; off < 1024; off <<= 1) {
        int add = (t >= off) ? s[t - off] : 0;
        __syncthreads();
        s[t] += add;
        __syncthreads();
    }
    int ex = s[t] - sum;
#pragma unroll
    for (int u = 0; u < SCAN_CH; ++u) {
        int i = base_i + u;
        if (i < N_NODES) {
            offsets[i] = ex;
            cursor[i]  = ex;
            dis[i] = rsqrtf((float)(v[u] + 1));
            ex += v[u];
        }
    }
    if (t == 1023) offsets[N_NODES] = s[1023];
}

__global__ __launch_bounds__(256) void k_fill(const int* __restrict__ row,
                                              const int* __restrict__ col,
                                              int* __restrict__ cursor,
                                              int* __restrict__ sorted_row) {
    int e = blockIdx.x * 256 + threadIdx.x;
    if (e < N_EDGES) {
        int c = col[e];
        int p = atomicAdd(&cursor[c], 1);
        sorted_row[p] = row[e];
    }
}

// ---------------------------------------------------------------- GEMM
// h_bf16[r][:] = bf16( dis[r] * (in[r][:] @ W) )
#define FMA4(acc, s, w)                    \
    acc.x = fmaf(s, w.x, acc.x);           \
    acc.y = fmaf(s, w.y, acc.y);           \
    acc.z = fmaf(s, w.z, acc.z);           \
    acc.w = fmaf(s, w.w, acc.w);

__global__ __launch_bounds__(256) void k_gemm_scale(const float* __restrict__ in,
                                                    const float* __restrict__ W,
                                                    const float* __restrict__ dis,
                                                    uint2* __restrict__ h2) {
    __shared__ float4 sW[128 * 32];  // 64 KB
    const float4* W4 = (const float4*)W;
    int cx = threadIdx.x;              // 0..31 (4 cols each)
    int tid = threadIdx.y * 32 + cx;
    for (int i = tid; i < 128 * 32; i += 256) sW[i] = W4[i];
    __syncthreads();

    int r0 = blockIdx.x * 32 + threadIdx.y * 4;
    if (r0 >= N_NODES) return;

    const float4* xr = (const float4*)(in + (size_t)r0 * D);
    float4 acc0 = {0, 0, 0, 0}, acc1 = {0, 0, 0, 0}, acc2 = {0, 0, 0, 0}, acc3 = {0, 0, 0, 0};

#pragma unroll 4
    for (int k4 = 0; k4 < 32; ++k4) {
        float4 a0 = xr[k4];
        float4 a1 = xr[32 + k4];
        float4 a2 = xr[64 + k4];
        float4 a3 = xr[96 + k4];
        float4 w;
        w = sW[(k4 * 4 + 0) * 32 + cx];
        FMA4(acc0, a0.x, w) FMA4(acc1, a1.x, w) FMA4(acc2, a2.x, w) FMA4(acc3, a3.x, w)
        w = sW[(k4 * 4 + 1) * 32 + cx];
        FMA4(acc0, a0.y, w) FMA4(acc1, a1.y, w) FMA4(acc2, a2.y, w) FMA4(acc3, a3.y, w)
        w = sW[(k4 * 4 + 2) * 32 + cx];
        FMA4(acc0, a0.z, w) FMA4(acc1, a1.z, w) FMA4(acc2, a2.z, w) FMA4(acc3, a3.z, w)
        w = sW[(k4 * 4 + 3) * 32 + cx];
        FMA4(acc0, a0.w, w) FMA4(acc1, a1.w, w) FMA4(acc2, a2.w, w) FMA4(acc3, a3.w, w)
    }

#pragma unroll
    for (int j = 0; j < 4; ++j) {
        float ds = dis[r0 + j];
        float4 a = (j == 0) ? acc0 : (j == 1) ? acc1 : (j == 2) ? acc2 : acc3;
        uint2 o;
        o.x = f2bf(a.x * ds) | (f2bf(a.y * ds) << 16);
        o.y = f2bf(a.z * ds) | (f2bf(a.w * ds) << 16);
        // row = 32 uint2; thread cx owns cols cx*4..cx*4+3 -> uint2 index cx
        h2[(size_t)(r0 + j) * 32 + cx] = o;
    }
}

// ---------------------------------------------------------------- gather
// out[c][:] = act( dis[c] * (h'[c] + sum_{e in CSR[c]} h'[row_e]) + b )
// one node per wave; 4 groups of 16 lanes each fetch a full 256B bf16 row
__global__ __launch_bounds__(256) void k_gather(const uint4* __restrict__ h4,
                                                const int* __restrict__ offsets,
                                                const int* __restrict__ sorted_row,
                                                const float* __restrict__ dis,
                                                const float* __restrict__ b,
                                                float* __restrict__ out, int relu) {
    int wave = threadIdx.x >> 6;
    int lane = threadIdx.x & 63;
    int c = blockIdx.x * 4 + wave;   // N_NODES = 4*2500 exact
    int g = lane >> 4;               // edge slot 0..3
    int l16 = lane & 15;             // 16B chunk of the row

    float acc[8] = {0.f, 0.f, 0.f, 0.f, 0.f, 0.f, 0.f, 0.f};

#define ADDROW(r)                                                     \
    {                                                                 \
        uint4 w = h4[(size_t)(r) * 16 + l16];                         \
        acc[0] += asf(w.x << 16); acc[1] += asf(w.x & 0xffff0000u);   \
        acc[2] += asf(w.y << 16); acc[3] += asf(w.y & 0xffff0000u);   \
        acc[4] += asf(w.z << 16); acc[5] += asf(w.z & 0xffff0000u);   \
        acc[6] += asf(w.w << 16); acc[7] += asf(w.w & 0xffff0000u);   \
    }

    if (g == 0) ADDROW(c);  // self loop

    int beg = offsets[c], end = offsets[c + 1];
    int j = beg + g;
    if (j < end) {
        int r = sorted_row[j];
        for (j += 4; j < end; j += 4) {
            int rn = sorted_row[j];   // prefetch next index
            ADDROW(r);
            r = rn;
        }
        ADDROW(r);
    }

#pragma unroll
    for (int k = 0; k < 8; ++k) {
        acc[k] += __shfl_xor(acc[k], 16);
        acc[k] += __shfl_xor(acc[k], 32);
    }

    if (g == 0) {
        float ds = dis[c];
        const float4* b4 = (const float4*)b;
        float4 bb0 = b4[l16 * 2];
        float4 bb1 = b4[l16 * 2 + 1];
        float4 o0, o1;
        o0.x = fmaf(ds, acc[0], bb0.x);
        o0.y = fmaf(ds, acc[1], bb0.y);
        o0.z = fmaf(ds, acc[2], bb0.z);
        o0.w = fmaf(ds, acc[3], bb0.w);
        o1.x = fmaf(ds, acc[4], bb1.x);
        o1.y = fmaf(ds, acc[5], bb1.y);
        o1.z = fmaf(ds, acc[6], bb1.z);
        o1.w = fmaf(ds, acc[7], bb1.w);
        if (relu) {
            o0.x = fmaxf(o0.x, 0.f); o0.y = fmaxf(o0.y, 0.f);
            o0.z = fmaxf(o0.z, 0.f); o0.w = fmaxf(o0.w, 0.f);
            o1.x = fmaxf(o1.x, 0.f); o1.y = fmaxf(o1.y, 0.f);
            o1.z = fmaxf(o1.z, 0.f); o1.w = fmaxf(o1.w, 0.f);
        }
        float4* op = (float4*)(out + (size_t)c * D + l16 * 8);
        op[0] = o0;
        op[1] = o1;
    }
#undef ADDROW
}

// ---------------------------------------------------------------- launch
extern "C" void kernel_launch(void* const* d_in, const int* in_sizes, int n_in,
                              void* d_out, int out_size, void* d_ws, size_t ws_size,
                              hipStream_t stream) {
    const float* x  = (const float*)d_in[0];
    const int*   ei = (const int*)d_in[1];
    const float* W1 = (const float*)d_in[2];
    const float* b1 = (const float*)d_in[3];
    const float* W2 = (const float*)d_in[4];
    const float* b2 = (const float*)d_in[5];

    float* out = (float*)d_out;
    float* x2 = out;                        // tuple elem 0
    float* x1 = out + (size_t)N_NODES * D;  // tuple elem 1

    const int* row = ei;
    const int* col = ei + N_EDGES;

    // workspace layout (16B-aligned chunks)
    int* cnt        = (int*)d_ws;                     // 10016
    int* offsets    = cnt + 10016;                    // 10016
    int* cursor     = offsets + 10016;                // 10016
    float* dis      = (float*)(cursor + 10016);       // 10016
    int* sorted_row = (int*)(dis + 10016);            // 640000
    unsigned int* h = (unsigned int*)(sorted_row + N_EDGES);  // bf16 h: 10000*128*2B = 2.56MB

    k_zero_i32<<<(N_NODES + 255) / 256, 256, 0, stream>>>(cnt, N_NODES);
    k_count<<<(N_EDGES + 255) / 256, 256, 0, stream>>>(col, cnt);
    k_scan<<<1, 1024, 0, stream>>>(cnt, offsets, cursor, dis);
    k_fill<<<(N_EDGES + 255) / 256, 256, 0, stream>>>(row, col, cursor, sorted_row);

    // layer 1
    k_gemm_scale<<<(N_NODES + 31) / 32, dim3(32, 8), 0, stream>>>(x, W1, dis, (uint2*)h);
    k_gather<<<N_NODES / 4, 256, 0, stream>>>((const uint4*)h, offsets, sorted_row, dis, b1, x1, 1);
    // layer 2
    k_gemm_scale<<<(N_NODES + 31) / 32, dim3(32, 8), 0, stream>>>(x1, W2, dis, (uint2*)h);
    k_gather<<<N_NODES / 4, 256, 0, stream>>>((const uint4*)h, offsets, sorted_row, dis, b2, x2, 0);
}

// Round 4
// 200.211 us; speedup vs baseline: 1.2609x; 1.1230x over previous
//
#include <hip/hip_runtime.h>

#define N_NODES 10000
#define N_EDGES 640000
#define D 128
#define NBUCK 157    // ceil(10000/64) buckets of 64 destination nodes
#define BSTRIDE 160
#define EPT 20       // edges per thread in k_bucket
#define BWG 125      // 125 * 256 * 20 == 640000 exactly

// ---------------------------------------------------------------- helpers
__device__ __forceinline__ float asf(unsigned int u) {
    union { unsigned int i; float f; } v; v.i = u; return v.f;
}
__device__ __forceinline__ unsigned int f2bf(float f) {
    union { float f; unsigned int i; } v; v.f = f;
    return (v.i + 0x7fffu + ((v.i >> 16) & 1u)) >> 16;  // RNE
}

// ---------------------------------------------------------------- utilities
__global__ __launch_bounds__(256) void k_zero_i32(int* __restrict__ p, int n) {
    int i = blockIdx.x * 256 + threadIdx.x;
    if (i < n) p[i] = 0;
}

__global__ __launch_bounds__(256) void k_count(const int* __restrict__ col,
                                               int* __restrict__ cnt) {
    int e = blockIdx.x * 256 + threadIdx.x;
    if (e < N_EDGES) atomicAdd(&cnt[col[e]], 1);
}

// single-block exclusive scan; dis = rsqrt(cnt+1); bucket_cursor[b] = offsets[64b]
#define SCAN_CH 10
__global__ __launch_bounds__(1024) void k_scan(const int* __restrict__ cnt,
                                               int* __restrict__ offsets,
                                               int* __restrict__ bucket_cursor,
                                               float* __restrict__ dis) {
    __shared__ int s[1024];
    int t = threadIdx.x;
    int base_i = t * SCAN_CH;
    int v[SCAN_CH];
    int sum = 0;
#pragma unroll
    for (int u = 0; u < SCAN_CH; ++u) {
        int i = base_i + u;
        int x = (i < N_NODES) ? cnt[i] : 0;
        v[u] = x;
        sum += x;
    }
    s[t] = sum;
    __syncthreads();
    for (int off = 1; off < 1024; off <<= 1) {
        int add = (t >= off) ? s[t - off] : 0;
        __syncthreads();
        s[t] += add;
        __syncthreads();
    }
    int ex = s[t] - sum;
#pragma unroll
    for (int u = 0; u < SCAN_CH; ++u) {
        int i = base_i + u;
        if (i < N_NODES) {
            offsets[i] = ex;
            if ((i & 63) == 0) bucket_cursor[i >> 6] = ex;  // coarse segment start
            dis[i] = rsqrtf((float)(v[u] + 1));
            ex += v[u];
        }
    }
    if (t == 1023) offsets[N_NODES] = s[1023];
}

// ---------------------------------------------------------------- multisplit
// pass A: bin edges by coarse bucket (col>>6) into per-bucket contiguous runs.
// word = row | (col << 14)   (row<16384, col<16384)
__global__ __launch_bounds__(256) void k_bucket(const int* __restrict__ row,
                                                const int* __restrict__ col,
                                                int* __restrict__ bucket_cursor,
                                                unsigned int* __restrict__ bucketed) {
    __shared__ int hist[BSTRIDE];
    __shared__ int base_s[BSTRIDE];
    int tid = threadIdx.x;
    if (tid < BSTRIDE) hist[tid] = 0;
    __syncthreads();

    int e0 = blockIdx.x * (256 * EPT) + tid;  // exact fit: no guards needed
    unsigned int word[EPT];
    int rank[EPT];
#pragma unroll
    for (int u = 0; u < EPT; ++u) {
        int e = e0 + u * 256;
        int r = row[e];
        int c = col[e];
        word[u] = (unsigned int)r | ((unsigned int)c << 14);
        rank[u] = atomicAdd(&hist[c >> 6], 1);
    }
    __syncthreads();
    if (tid < NBUCK) base_s[tid] = atomicAdd(&bucket_cursor[tid], hist[tid]);
    __syncthreads();
#pragma unroll
    for (int u = 0; u < EPT; ++u) {
        int bkt = (int)(word[u] >> 20);  // == col >> 6
        bucketed[base_s[bkt] + rank[u]] = word[u];
    }
}

// pass B: one WG per bucket; fine placement via LDS cursors.
// writes stay inside the bucket's contiguous CSR segment (~16KB, L2-local).
__global__ __launch_bounds__(256) void k_place(const unsigned int* __restrict__ bucketed,
                                               const int* __restrict__ offsets,
                                               int* __restrict__ sorted_row) {
    __shared__ int cur[64];
    int b = blockIdx.x;
    int tid = threadIdx.x;
    int n0 = b << 6;
    if (tid < 64 && n0 + tid < N_NODES) cur[tid] = offsets[n0 + tid];
    __syncthreads();
    int nend = n0 + 64;
    if (nend > N_NODES) nend = N_NODES;
    int seg_beg = offsets[n0];
    int seg_end = offsets[nend];
    for (int k = seg_beg + tid; k < seg_end; k += 256) {
        unsigned int w = bucketed[k];
        int cl = (int)(w >> 14) & 63;
        int r = (int)(w & 0x3FFFu);
        int p = atomicAdd(&cur[cl], 1);
        sorted_row[p] = r;
    }
}

// ---------------------------------------------------------------- GEMM
// h_bf16[r][:] = bf16( dis[r] * (in[r][:] @ W) )
#define FMA4(acc, s, w)                    \
    acc.x = fmaf(s, w.x, acc.x);           \
    acc.y = fmaf(s, w.y, acc.y);           \
    acc.z = fmaf(s, w.z, acc.z);           \
    acc.w = fmaf(s, w.w, acc.w);

__global__ __launch_bounds__(256) void k_gemm_scale(const float* __restrict__ in,
                                                    const float* __restrict__ W,
                                                    const float* __restrict__ dis,
                                                    uint2* __restrict__ h2) {
    __shared__ float4 sW[128 * 32];  // 64 KB
    const float4* W4 = (const float4*)W;
    int cx = threadIdx.x;
    int tid = threadIdx.y * 32 + cx;
    for (int i = tid; i < 128 * 32; i += 256) sW[i] = W4[i];
    __syncthreads();

    int r0 = blockIdx.x * 32 + threadIdx.y * 4;
    if (r0 >= N_NODES) return;

    const float4* xr = (const float4*)(in + (size_t)r0 * D);
    float4 acc0 = {0, 0, 0, 0}, acc1 = {0, 0, 0, 0}, acc2 = {0, 0, 0, 0}, acc3 = {0, 0, 0, 0};

#pragma unroll 4
    for (int k4 = 0; k4 < 32; ++k4) {
        float4 a0 = xr[k4];
        float4 a1 = xr[32 + k4];
        float4 a2 = xr[64 + k4];
        float4 a3 = xr[96 + k4];
        float4 w;
        w = sW[(k4 * 4 + 0) * 32 + cx];
        FMA4(acc0, a0.x, w) FMA4(acc1, a1.x, w) FMA4(acc2, a2.x, w) FMA4(acc3, a3.x, w)
        w = sW[(k4 * 4 + 1) * 32 + cx];
        FMA4(acc0, a0.y, w) FMA4(acc1, a1.y, w) FMA4(acc2, a2.y, w) FMA4(acc3, a3.y, w)
        w = sW[(k4 * 4 + 2) * 32 + cx];
        FMA4(acc0, a0.z, w) FMA4(acc1, a1.z, w) FMA4(acc2, a2.z, w) FMA4(acc3, a3.z, w)
        w = sW[(k4 * 4 + 3) * 32 + cx];
        FMA4(acc0, a0.w, w) FMA4(acc1, a1.w, w) FMA4(acc2, a2.w, w) FMA4(acc3, a3.w, w)
    }

#pragma unroll
    for (int j = 0; j < 4; ++j) {
        float ds = dis[r0 + j];
        float4 a = (j == 0) ? acc0 : (j == 1) ? acc1 : (j == 2) ? acc2 : acc3;
        uint2 o;
        o.x = f2bf(a.x * ds) | (f2bf(a.y * ds) << 16);
        o.y = f2bf(a.z * ds) | (f2bf(a.w * ds) << 16);
        h2[(size_t)(r0 + j) * 32 + cx] = o;
    }
}

// ---------------------------------------------------------------- gather
// one node per wave; 8 groups of 8 lanes each fetch a 256B bf16 row (2 uint4/lane)
__global__ __launch_bounds__(256) void k_gather(const uint4* __restrict__ h4,
                                                const int* __restrict__ offsets,
                                                const int* __restrict__ sorted_row,
                                                const float* __restrict__ dis,
                                                const float* __restrict__ b,
                                                float* __restrict__ out, int relu) {
    int wave = threadIdx.x >> 6;
    int lane = threadIdx.x & 63;
    int c = blockIdx.x * 4 + wave;   // N_NODES = 4*2500 exact
    int g = lane >> 3;               // edge slot 0..7
    int l8 = lane & 7;               // 32B chunk of the row

    float acc[16];
#pragma unroll
    for (int k = 0; k < 16; ++k) acc[k] = 0.f;

#define ADDROW(r)                                                        \
    {                                                                    \
        const uint4* p = &h4[(size_t)(r) * 16 + l8 * 2];                 \
        uint4 w0 = p[0];                                                 \
        uint4 w1 = p[1];                                                 \
        acc[0]  += asf(w0.x << 16); acc[1]  += asf(w0.x & 0xffff0000u);  \
        acc[2]  += asf(w0.y << 16); acc[3]  += asf(w0.y & 0xffff0000u);  \
        acc[4]  += asf(w0.z << 16); acc[5]  += asf(w0.z & 0xffff0000u);  \
        acc[6]  += asf(w0.w << 16); acc[7]  += asf(w0.w & 0xffff0000u);  \
        acc[8]  += asf(w1.x << 16); acc[9]  += asf(w1.x & 0xffff0000u);  \
        acc[10] += asf(w1.y << 16); acc[11] += asf(w1.y & 0xffff0000u);  \
        acc[12] += asf(w1.z << 16); acc[13] += asf(w1.z & 0xffff0000u);  \
        acc[14] += asf(w1.w << 16); acc[15] += asf(w1.w & 0xffff0000u);  \
    }

    if (g == 0) ADDROW(c);  // self loop

    int beg = offsets[c], end = offsets[c + 1];
    int j = beg + g;
    if (j < end) {
        int r = sorted_row[j];
        for (j += 8; j < end; j += 8) {
            int rn = sorted_row[j];  // prefetch next index
            ADDROW(r);
            r = rn;
        }
        ADDROW(r);
    }
#undef ADDROW

#pragma unroll
    for (int k = 0; k < 16; ++k) {
        acc[k] += __shfl_xor(acc[k], 8);
        acc[k] += __shfl_xor(acc[k], 16);
        acc[k] += __shfl_xor(acc[k], 32);
    }

    if (g == 0) {
        float ds = dis[c];
        const float4* b4 = (const float4*)b;
        float4* op = (float4*)(out + (size_t)c * D + l8 * 16);
#pragma unroll
        for (int q = 0; q < 4; ++q) {
            float4 bb = b4[l8 * 4 + q];
            float4 o;
            o.x = fmaf(ds, acc[q * 4 + 0], bb.x);
            o.y = fmaf(ds, acc[q * 4 + 1], bb.y);
            o.z = fmaf(ds, acc[q * 4 + 2], bb.z);
            o.w = fmaf(ds, acc[q * 4 + 3], bb.w);
            if (relu) {
                o.x = fmaxf(o.x, 0.f); o.y = fmaxf(o.y, 0.f);
                o.z = fmaxf(o.z, 0.f); o.w = fmaxf(o.w, 0.f);
            }
            op[q] = o;
        }
    }
}

// ---------------------------------------------------------------- launch
extern "C" void kernel_launch(void* const* d_in, const int* in_sizes, int n_in,
                              void* d_out, int out_size, void* d_ws, size_t ws_size,
                              hipStream_t stream) {
    const float* x  = (const float*)d_in[0];
    const int*   ei = (const int*)d_in[1];
    const float* W1 = (const float*)d_in[2];
    const float* b1 = (const float*)d_in[3];
    const float* W2 = (const float*)d_in[4];
    const float* b2 = (const float*)d_in[5];

    float* out = (float*)d_out;
    float* x2 = out;                        // tuple elem 0
    float* x1 = out + (size_t)N_NODES * D;  // tuple elem 1

    const int* row = ei;
    const int* col = ei + N_EDGES;

    // workspace layout (16B-aligned chunks)
    int* cnt            = (int*)d_ws;                       // 10016
    int* offsets        = cnt + 10016;                      // 10016 (needs 10001)
    int* bucket_cursor  = offsets + 10016;                  // 160
    float* dis          = (float*)(bucket_cursor + BSTRIDE);// 10016
    unsigned int* bucketed = (unsigned int*)(dis + 10016);  // 640000
    int* sorted_row     = (int*)(bucketed + N_EDGES);       // 640000
    unsigned int* h     = (unsigned int*)(sorted_row + N_EDGES);  // 640000 u32 (bf16 pairs)

    k_zero_i32<<<(N_NODES + 255) / 256, 256, 0, stream>>>(cnt, N_NODES);
    k_count<<<(N_EDGES + 255) / 256, 256, 0, stream>>>(col, cnt);
    k_scan<<<1, 1024, 0, stream>>>(cnt, offsets, bucket_cursor, dis);
    k_bucket<<<BWG, 256, 0, stream>>>(row, col, bucket_cursor, bucketed);
    k_place<<<NBUCK, 256, 0, stream>>>(bucketed, offsets, sorted_row);

    // layer 1
    k_gemm_scale<<<(N_NODES + 31) / 32, dim3(32, 8), 0, stream>>>(x, W1, dis, (uint2*)h);
    k_gather<<<N_NODES / 4, 256, 0, stream>>>((const uint4*)h, offsets, sorted_row, dis, b1, x1, 1);
    // layer 2
    k_gemm_scale<<<(N_NODES + 31) / 32, dim3(32, 8), 0, stream>>>(x1, W2, dis, (uint2*)h);
    k_gather<<<N_NODES / 4, 256, 0, stream>>>((const uint4*)h, offsets, sorted_row, dis, b2, x2, 0);
}

// Round 6
// 152.787 us; speedup vs baseline: 1.6523x; 1.3104x over previous
//
#include <hip/hip_runtime.h>

#define N_NODES 10000
#define N_EDGES 640000
#define D 128
#define NBUCK 157     // ceil(10000/64) buckets of 64 destination nodes
#define BSTRIDE 160
#define CAP 4608      // slab capacity per bucket (mean 4096, sigma~64, +8 sigma)
#define EPT 20        // edges per thread in k_bucket
#define BWG 125       // 125 * 256 * 20 == 640000 exactly

// ---------------------------------------------------------------- helpers
__device__ __forceinline__ float asf(unsigned int u) {
    union { unsigned int i; float f; } v; v.i = u; return v.f;
}
__device__ __forceinline__ unsigned int f2bf(float f) {
    union { float f; unsigned int i; } v; v.f = f;
    return (v.i + 0x7fffu + ((v.i >> 16) & 1u)) >> 16;  // RNE
}

// ---------------------------------------------------------------- zero (tiny)
__global__ __launch_bounds__(256) void k_zero_small(int* __restrict__ slab_cnt,
                                                    int* __restrict__ gcur) {
    int t = threadIdx.x;
    if (t < BSTRIDE) slab_cnt[t] = 0;
    if (t == 0) gcur[0] = 0;
}

// ---------------------------------------------------------------- multisplit A
// bin edges by coarse bucket (col>>6) into fixed-capacity slabs.
// word = row | (col << 14)
__global__ __launch_bounds__(256) void k_bucket(const int* __restrict__ row,
                                                const int* __restrict__ col,
                                                int* __restrict__ slab_cnt,
                                                unsigned int* __restrict__ bucketed) {
    __shared__ int hist[BSTRIDE];
    __shared__ int base_s[BSTRIDE];
    int tid = threadIdx.x;
    if (tid < BSTRIDE) hist[tid] = 0;
    __syncthreads();

    int e0 = blockIdx.x * (256 * EPT) + tid;  // exact fit
    unsigned int word[EPT];
    int rank[EPT];
#pragma unroll
    for (int u = 0; u < EPT; ++u) {
        int e = e0 + u * 256;
        int r = row[e];
        int c = col[e];
        word[u] = (unsigned int)r | ((unsigned int)c << 14);
        rank[u] = atomicAdd(&hist[c >> 6], 1);
    }
    __syncthreads();
    if (tid < NBUCK) base_s[tid] = atomicAdd(&slab_cnt[tid], hist[tid]);
    __syncthreads();
#pragma unroll
    for (int u = 0; u < EPT; ++u) {
        int bkt = (int)(word[u] >> 20);  // == col >> 6
        int idx = base_s[bkt] + rank[u];
        if (idx < CAP) bucketed[(size_t)bkt * CAP + idx] = word[u];
    }
}

// ---------------------------------------------------------------- multisplit B
// one WG per bucket: LDS histogram -> local scan -> one global cursor reserve
// -> emit node_be / dis / sorted_row. No global scan kernel needed.
__global__ __launch_bounds__(256) void k_place(const unsigned int* __restrict__ bucketed,
                                               const int* __restrict__ slab_cnt,
                                               int* __restrict__ gcur,
                                               int* __restrict__ sorted_row,
                                               int2* __restrict__ node_be,
                                               float* __restrict__ dis) {
    __shared__ int hist[64];
    __shared__ int start[64];
    __shared__ int cur[64];
    __shared__ int baseS;
    int b = blockIdx.x;
    int tid = threadIdx.x;
    if (tid < 64) hist[tid] = 0;
    __syncthreads();

    int scnt = slab_cnt[b];
    if (scnt > CAP) scnt = CAP;
    const unsigned int* slab = bucketed + (size_t)b * CAP;

    for (int k = tid; k < scnt; k += 256) {
        int cl = (int)(slab[k] >> 14) & 63;
        atomicAdd(&hist[cl], 1);
    }
    __syncthreads();

    if (tid < 64) {  // wave 0: inclusive shfl scan -> exclusive starts
        int v = hist[tid];
        int pre = v;
#pragma unroll
        for (int off = 1; off < 64; off <<= 1) {
            int o = __shfl_up(pre, off);
            if (tid >= off) pre += o;
        }
        start[tid] = pre - v;
        if (tid == 63) baseS = atomicAdd(gcur, pre);  // reserve segment
    }
    __syncthreads();
    int base = baseS;
    if (tid < 64) {
        int c = (b << 6) + tid;
        if (c < N_NODES) {
            int beg = base + start[tid];
            node_be[c] = make_int2(beg, beg + hist[tid]);
            dis[c] = rsqrtf((float)(hist[tid] + 1));  // +1 self loop
        }
        cur[tid] = start[tid];
    }
    __syncthreads();

    for (int k = tid; k < scnt; k += 256) {
        unsigned int w = slab[k];
        int cl = (int)(w >> 14) & 63;
        int r = (int)(w & 0x3FFFu);
        int p = atomicAdd(&cur[cl], 1);
        sorted_row[base + p] = r;
    }
}

// ---------------------------------------------------------------- GEMM
// h_bf16[r][:] = bf16( dis[r] * (in[r][:] @ W) )
// grid = 313 row-tiles x 2 col-halves; block (16,16); 32KB LDS; 2 rows/thread
#define FMA4(acc, s, w)                    \
    acc.x = fmaf(s, w.x, acc.x);           \
    acc.y = fmaf(s, w.y, acc.y);           \
    acc.z = fmaf(s, w.z, acc.z);           \
    acc.w = fmaf(s, w.w, acc.w);

__global__ __launch_bounds__(256) void k_gemm_scale(const float* __restrict__ in,
                                                    const float* __restrict__ W,
                                                    const float* __restrict__ dis,
                                                    uint2* __restrict__ h2) {
    __shared__ float4 sW[128 * 16];  // 32 KB: this half's 64 cols
    const float4* W4 = (const float4*)W;
    int half = blockIdx.x & 1;
    int tile = blockIdx.x >> 1;
    int cx = threadIdx.x;            // 0..15 -> float4 col group within half
    int ty = threadIdx.y;            // 0..15 -> 2 rows each
    int tid = ty * 16 + cx;
    for (int i = tid; i < 128 * 16; i += 256) {
        int k = i >> 4, q = i & 15;
        sW[i] = W4[k * 32 + half * 16 + q];
    }
    __syncthreads();

    int r0 = tile * 32 + ty * 2;
    if (r0 >= N_NODES) return;  // no barriers after this point

    const float4* xr = (const float4*)(in + (size_t)r0 * D);
    float4 acc0 = {0, 0, 0, 0}, acc1 = {0, 0, 0, 0};

#pragma unroll 4
    for (int k4 = 0; k4 < 32; ++k4) {
        float4 a0 = xr[k4];
        float4 a1 = xr[32 + k4];
        float4 w;
        w = sW[(k4 * 4 + 0) * 16 + cx];
        FMA4(acc0, a0.x, w) FMA4(acc1, a1.x, w)
        w = sW[(k4 * 4 + 1) * 16 + cx];
        FMA4(acc0, a0.y, w) FMA4(acc1, a1.y, w)
        w = sW[(k4 * 4 + 2) * 16 + cx];
        FMA4(acc0, a0.z, w) FMA4(acc1, a1.z, w)
        w = sW[(k4 * 4 + 3) * 16 + cx];
        FMA4(acc0, a0.w, w) FMA4(acc1, a1.w, w)
    }

#pragma unroll
    for (int j = 0; j < 2; ++j) {
        float ds = dis[r0 + j];
        float4 a = j ? acc1 : acc0;
        uint2 o;
        o.x = f2bf(a.x * ds) | (f2bf(a.y * ds) << 16);
        o.y = f2bf(a.z * ds) | (f2bf(a.w * ds) << 16);
        h2[(size_t)(r0 + j) * 32 + half * 16 + cx] = o;
    }
}

// ---------------------------------------------------------------- gather
// one node per wave; 8 groups of 8 lanes; 2-deep idx prefetch + row dbuf
__global__ __launch_bounds__(256) void k_gather(const uint4* __restrict__ h4,
                                                const int2* __restrict__ node_be,
                                                const int* __restrict__ sorted_row,
                                                const float* __restrict__ dis,
                                                const float* __restrict__ b,
                                                float* __restrict__ out, int relu) {
    int wave = threadIdx.x >> 6;
    int lane = threadIdx.x & 63;
    int c = blockIdx.x * 4 + wave;   // N_NODES = 4*2500 exact
    int g = lane >> 3;               // edge slot 0..7
    int l8 = lane & 7;               // 32B chunk of the row

    float acc[16];
#pragma unroll
    for (int k = 0; k < 16; ++k) acc[k] = 0.f;

#define LOADROW(r, wa, wb)                                  \
    {                                                       \
        const uint4* p = &h4[(size_t)(r) * 16 + l8 * 2];    \
        wa = p[0]; wb = p[1];                               \
    }
#define ACCUM(wa, wb)                                                    \
    {                                                                    \
        acc[0]  += asf(wa.x << 16); acc[1]  += asf(wa.x & 0xffff0000u);  \
        acc[2]  += asf(wa.y << 16); acc[3]  += asf(wa.y & 0xffff0000u);  \
        acc[4]  += asf(wa.z << 16); acc[5]  += asf(wa.z & 0xffff0000u);  \
        acc[6]  += asf(wa.w << 16); acc[7]  += asf(wa.w & 0xffff0000u);  \
        acc[8]  += asf(wb.x << 16); acc[9]  += asf(wb.x & 0xffff0000u);  \
        acc[10] += asf(wb.y << 16); acc[11] += asf(wb.y & 0xffff0000u);  \
        acc[12] += asf(wb.z << 16); acc[13] += asf(wb.z & 0xffff0000u);  \
        acc[14] += asf(wb.w << 16); acc[15] += asf(wb.w & 0xffff0000u);  \
    }

    if (g == 0) {  // self loop
        uint4 s0, s1;
        LOADROW(c, s0, s1);
        ACCUM(s0, s1);
    }

    int2 be = node_be[c];
    int end = be.y;
    int j = be.x + g;
    if (j < end) {
        int r_cur = sorted_row[j];
        uint4 c0, c1;
        LOADROW(r_cur, c0, c1);
        int j1 = j + 8;
        int r_nxt = (j1 < end) ? sorted_row[j1] : 0;
        while (j1 < end) {
            int j2 = j1 + 8;
            int r_nn = (j2 < end) ? sorted_row[j2] : 0;  // idx 2 ahead
            uint4 n0, n1;
            LOADROW(r_nxt, n0, n1);                      // row 1 ahead
            ACCUM(c0, c1);                               // current from regs
            c0 = n0; c1 = n1;
            r_nxt = r_nn;
            j1 = j2;
        }
        ACCUM(c0, c1);
    }
#undef LOADROW
#undef ACCUM

#pragma unroll
    for (int k = 0; k < 16; ++k) {
        acc[k] += __shfl_xor(acc[k], 8);
        acc[k] += __shfl_xor(acc[k], 16);
        acc[k] += __shfl_xor(acc[k], 32);
    }

    if (g == 0) {
        float ds = dis[c];
        const float4* b4 = (const float4*)b;
        float4* op = (float4*)(out + (size_t)c * D + l8 * 16);
#pragma unroll
        for (int q = 0; q < 4; ++q) {
            float4 bb = b4[l8 * 4 + q];
            float4 o;
            o.x = fmaf(ds, acc[q * 4 + 0], bb.x);
            o.y = fmaf(ds, acc[q * 4 + 1], bb.y);
            o.z = fmaf(ds, acc[q * 4 + 2], bb.z);
            o.w = fmaf(ds, acc[q * 4 + 3], bb.w);
            if (relu) {
                o.x = fmaxf(o.x, 0.f); o.y = fmaxf(o.y, 0.f);
                o.z = fmaxf(o.z, 0.f); o.w = fmaxf(o.w, 0.f);
            }
            op[q] = o;
        }
    }
}

// ---------------------------------------------------------------- launch
extern "C" void kernel_launch(void* const* d_in, const int* in_sizes, int n_in,
                              void* d_out, int out_size, void* d_ws, size_t ws_size,
                              hipStream_t stream) {
    const float* x  = (const float*)d_in[0];
    const int*   ei = (const int*)d_in[1];
    const float* W1 = (const float*)d_in[2];
    const float* b1 = (const float*)d_in[3];
    const float* W2 = (const float*)d_in[4];
    const float* b2 = (const float*)d_in[5];

    float* out = (float*)d_out;
    float* x2 = out;                        // tuple elem 0
    float* x1 = out + (size_t)N_NODES * D;  // tuple elem 1

    const int* row = ei;
    const int* col = ei + N_EDGES;

    // workspace layout (16B-aligned chunks)
    int* slab_cnt       = (int*)d_ws;                          // 160
    int* gcur           = slab_cnt + BSTRIDE;                  // 16
    float* dis          = (float*)(gcur + 16);                 // 10016
    int2* node_be       = (int2*)(dis + 10016);                // 10000 int2
    unsigned int* bucketed = (unsigned int*)(node_be + 10016); // 157*4608 = 723456
    int* sorted_row     = (int*)(bucketed + (size_t)NBUCK * CAP); // 640000
    unsigned int* h     = (unsigned int*)(sorted_row + N_EDGES);  // 640000 u32

    k_zero_small<<<1, 256, 0, stream>>>(slab_cnt, gcur);
    k_bucket<<<BWG, 256, 0, stream>>>(row, col, slab_cnt, bucketed);
    k_place<<<NBUCK, 256, 0, stream>>>(bucketed, slab_cnt, gcur, sorted_row, node_be, dis);

    // layer 1
    k_gemm_scale<<<626, dim3(16, 16), 0, stream>>>(x, W1, dis, (uint2*)h);
    k_gather<<<N_NODES / 4, 256, 0, stream>>>((const uint4*)h, node_be, sorted_row, dis, b1, x1, 1);
    // layer 2
    k_gemm_scale<<<626, dim3(16, 16), 0, stream>>>(x1, W2, dis, (uint2*)h);
    k_gather<<<N_NODES / 4, 256, 0, stream>>>((const uint4*)h, node_be, sorted_row, dis, b2, x2, 0);
}

// Round 8
// 148.102 us; speedup vs baseline: 1.7046x; 1.0316x over previous
//
#include <hip/hip_runtime.h>

#define N_NODES 10000
#define N_EDGES 640000
#define D 128
#define NBUCK 157      // ceil(10000/64) buckets of 64 destination nodes
#define BSTRIDE 160
#define CAP 4608       // sorted_row capacity per bucket (mean 4076 + 8.3 sigma)
#define CAP_BB 80      // per (block,bucket) chunk capacity (mean 32.6 + 8.3 sigma)
#define BWG 125        // bucket blocks; 125 * 5120 == 640000 exactly
#define SLOTS (BWG * CAP_BB)  // 10000 slots per bucket

// ---------------------------------------------------------------- helpers
__device__ __forceinline__ float asf(unsigned int u) {
    union { unsigned int i; float f; } v; v.i = u; return v.f;
}
__device__ __forceinline__ unsigned int f2bf(float f) {
    union { float f; unsigned int i; } v; v.f = f;
    return (v.i + 0x7fffu + ((v.i >> 16) & 1u)) >> 16;  // RNE
}

// ---------------------------------------------------------------- bucket
// bin edges into private per-(block,bucket) chunks; no global atomics.
// word = row | (col << 14);  bkt = word >> 20 == col >> 6
__global__ __launch_bounds__(256) void k_bucket(const int4* __restrict__ row4,
                                                const int4* __restrict__ col4,
                                                unsigned short* __restrict__ cnt_bb,
                                                unsigned int* __restrict__ bucketed) {
    __shared__ int hist[BSTRIDE];
    int tid = threadIdx.x;
    if (tid < BSTRIDE) hist[tid] = 0;
    __syncthreads();

    int base4 = blockIdx.x * 1280;  // 1280 int4 = 5120 edges per block, exact fit
    unsigned int word[20];
    int rank[20];
#pragma unroll
    for (int u = 0; u < 5; ++u) {
        int4 r = row4[base4 + u * 256 + tid];
        int4 c = col4[base4 + u * 256 + tid];
        int e = u * 4;
        word[e+0] = (unsigned)r.x | ((unsigned)c.x << 14); rank[e+0] = atomicAdd(&hist[c.x >> 6], 1);
        word[e+1] = (unsigned)r.y | ((unsigned)c.y << 14); rank[e+1] = atomicAdd(&hist[c.y >> 6], 1);
        word[e+2] = (unsigned)r.z | ((unsigned)c.z << 14); rank[e+2] = atomicAdd(&hist[c.z >> 6], 1);
        word[e+3] = (unsigned)r.w | ((unsigned)c.w << 14); rank[e+3] = atomicAdd(&hist[c.w >> 6], 1);
    }
    __syncthreads();
    if (tid < NBUCK) {
        int h = hist[tid];
        cnt_bb[tid * 128 + blockIdx.x] = (unsigned short)(h < CAP_BB ? h : CAP_BB);
    }
#pragma unroll
    for (int u = 0; u < 20; ++u) {
        int bkt = (int)(word[u] >> 20);
        if (rank[u] < CAP_BB)
            bucketed[(size_t)bkt * SLOTS + blockIdx.x * CAP_BB + rank[u]] = word[u];
    }
}

// ---------------------------------------------------------------- GEMM body
#define FMA4(acc, s, w)                    \
    acc.x = fmaf(s, w.x, acc.x);           \
    acc.y = fmaf(s, w.y, acc.y);           \
    acc.z = fmaf(s, w.z, acc.z);           \
    acc.w = fmaf(s, w.w, acc.w);

// h_bf16[r][:] = bf16( (SCALE ? dis[r] : 1) * (in[r][:] @ W) )
// gb in [0, 626): 313 row-tiles x 2 col-halves; 256 threads; 32KB LDS
template <bool SCALE>
__device__ __forceinline__ void gemm_body(int gb, int tid,
                                          const float* __restrict__ in,
                                          const float* __restrict__ W,
                                          const float* __restrict__ dis,
                                          uint2* __restrict__ h2,
                                          float4* sW) {
    const float4* W4 = (const float4*)W;
    int half = gb & 1;
    int tile = gb >> 1;
    int cx = tid & 15;
    int ty = tid >> 4;
    for (int i = tid; i < 128 * 16; i += 256) {
        int k = i >> 4, q = i & 15;
        sW[i] = W4[k * 32 + half * 16 + q];
    }
    __syncthreads();

    int r0 = tile * 32 + ty * 2;
    if (r0 >= N_NODES) return;  // no barriers after this point

    const float4* xr = (const float4*)(in + (size_t)r0 * D);
    float4 acc0 = {0, 0, 0, 0}, acc1 = {0, 0, 0, 0};
#pragma unroll 4
    for (int k4 = 0; k4 < 32; ++k4) {
        float4 a0 = xr[k4];
        float4 a1 = xr[32 + k4];
        float4 w;
        w = sW[(k4 * 4 + 0) * 16 + cx];
        FMA4(acc0, a0.x, w) FMA4(acc1, a1.x, w)
        w = sW[(k4 * 4 + 1) * 16 + cx];
        FMA4(acc0, a0.y, w) FMA4(acc1, a1.y, w)
        w = sW[(k4 * 4 + 2) * 16 + cx];
        FMA4(acc0, a0.z, w) FMA4(acc1, a1.z, w)
        w = sW[(k4 * 4 + 3) * 16 + cx];
        FMA4(acc0, a0.w, w) FMA4(acc1, a1.w, w)
    }
#pragma unroll
    for (int j = 0; j < 2; ++j) {
        float4 a = j ? acc1 : acc0;
        uint2 o;
        if (SCALE) {
            float ds = dis[r0 + j];
            o.x = f2bf(a.x * ds) | (f2bf(a.y * ds) << 16);
            o.y = f2bf(a.z * ds) | (f2bf(a.w * ds) << 16);
        } else {
            o.x = f2bf(a.x) | (f2bf(a.y) << 16);
            o.y = f2bf(a.z) | (f2bf(a.w) << 16);
        }
        h2[(size_t)(r0 + j) * 32 + half * 16 + cx] = o;
    }
}

// ---------------------------------------------------------------- fused place | gemm1
// blocks [0,157): CSR fine-placement; blocks [157,783): layer-1 GEMM (unscaled).
// Legal to fuse: gemm1 does not need dis (applied per-row in gather1).
__global__ __launch_bounds__(256) void k_fused1(const unsigned int* __restrict__ bucketed,
                                                const unsigned short* __restrict__ cnt_bb,
                                                int* __restrict__ sorted_row,
                                                int2* __restrict__ node_be,
                                                float* __restrict__ dis,
                                                const float* __restrict__ x,
                                                const float* __restrict__ W1,
                                                uint2* __restrict__ h2) {
    __shared__ __align__(16) char smem[32768];
    int tid = threadIdx.x;
    if (blockIdx.x >= NBUCK) {
        gemm_body<false>(blockIdx.x - NBUCK, tid, x, W1, nullptr, h2, (float4*)smem);
        return;
    }
    // ---- place role ----
    int* hist = (int*)smem;                              // 64
    int* cur  = hist + 64;                               // 64
    unsigned short* cnt_l = (unsigned short*)(cur + 64); // 128
    int b = blockIdx.x;
    if (tid < 64) hist[tid] = 0;
    if (tid < BWG) cnt_l[tid] = cnt_bb[b * 128 + tid];
    __syncthreads();

    const unsigned int* slab = bucketed + (size_t)b * SLOTS;
    for (int k = tid; k < SLOTS; k += 256) {           // pass 1: per-node histogram
        int blk = k / CAP_BB;
        int idx = k - blk * CAP_BB;
        if (idx < (int)cnt_l[blk]) {
            unsigned int w = slab[k];
            atomicAdd(&hist[(w >> 14) & 63], 1);
        }
    }
    __syncthreads();
    if (tid < 64) {  // wave 0: inclusive shfl scan -> segment layout + dis
        int v = hist[tid], pre = v;
#pragma unroll
        for (int off = 1; off < 64; off <<= 1) {
            int o = __shfl_up(pre, off);
            if (tid >= off) pre += o;
        }
        cur[tid] = pre - v;
        int c = (b << 6) + tid;
        if (c < N_NODES) {
            node_be[c] = make_int2(b * CAP + pre - v, b * CAP + pre);
            dis[c] = rsqrtf((float)(v + 1));  // +1 self loop
        }
    }
    __syncthreads();
    for (int k = tid; k < SLOTS; k += 256) {           // pass 2: scatter into segment
        int blk = k / CAP_BB;
        int idx = k - blk * CAP_BB;
        if (idx < (int)cnt_l[blk]) {
            unsigned int w = slab[k];
            int p = atomicAdd(&cur[(w >> 14) & 63], 1);
            sorted_row[b * CAP + p] = (int)(w & 0x3FFFu);
        }
    }
}

__global__ __launch_bounds__(256) void k_gemm2(const float* __restrict__ in,
                                               const float* __restrict__ W,
                                               const float* __restrict__ dis,
                                               uint2* __restrict__ h2) {
    __shared__ __align__(16) float4 sW[128 * 16];
    gemm_body<true>(blockIdx.x, threadIdx.x, in, W, dis, h2, sW);
}

// ---------------------------------------------------------------- gather
// one node per wave; 8 groups of 8 lanes; 2-deep idx prefetch + row dbuf.
// MODE 1: rows unscaled -> acc += dis[r]*h[r], + relu epilogue (layer 1)
// MODE 0: rows pre-scaled -> plain sum, no relu (layer 2)
template <int MODE>
__global__ __launch_bounds__(256) void k_gather(const uint4* __restrict__ h4,
                                                const int2* __restrict__ node_be,
                                                const int* __restrict__ sorted_row,
                                                const float* __restrict__ dis,
                                                const float* __restrict__ b,
                                                float* __restrict__ out) {
    int wave = threadIdx.x >> 6;
    int lane = threadIdx.x & 63;
    int c = blockIdx.x * 4 + wave;   // N_NODES = 4*2500 exact
    int g = lane >> 3;               // edge slot 0..7
    int l8 = lane & 7;               // 32B chunk of the row

    float acc[16];
#pragma unroll
    for (int k = 0; k < 16; ++k) acc[k] = 0.f;

#define LOADROW(r, wa, wb)                                  \
    {                                                       \
        const uint4* p = &h4[(size_t)(r) * 16 + l8 * 2];    \
        wa = p[0]; wb = p[1];                               \
    }
#define ACCUMS(wa, wb, s)                                                            \
    {                                                                                \
        acc[0]  = fmaf(s, asf(wa.x << 16), acc[0]);                                  \
        acc[1]  = fmaf(s, asf(wa.x & 0xffff0000u), acc[1]);                          \
        acc[2]  = fmaf(s, asf(wa.y << 16), acc[2]);                                  \
        acc[3]  = fmaf(s, asf(wa.y & 0xffff0000u), acc[3]);                          \
        acc[4]  = fmaf(s, asf(wa.z << 16), acc[4]);                                  \
        acc[5]  = fmaf(s, asf(wa.z & 0xffff0000u), acc[5]);                          \
        acc[6]  = fmaf(s, asf(wa.w << 16), acc[6]);                                  \
        acc[7]  = fmaf(s, asf(wa.w & 0xffff0000u), acc[7]);                          \
        acc[8]  = fmaf(s, asf(wb.x << 16), acc[8]);                                  \
        acc[9]  = fmaf(s, asf(wb.x & 0xffff0000u), acc[9]);                          \
        acc[10] = fmaf(s, asf(wb.y << 16), acc[10]);                                 \
        acc[11] = fmaf(s, asf(wb.y & 0xffff0000u), acc[11]);                         \
        acc[12] = fmaf(s, asf(wb.z << 16), acc[12]);                                 \
        acc[13] = fmaf(s, asf(wb.z & 0xffff0000u), acc[13]);                         \
        acc[14] = fmaf(s, asf(wb.w << 16), acc[14]);                                 \
        acc[15] = fmaf(s, asf(wb.w & 0xffff0000u), acc[15]);                         \
    }

    if (g == 0) {  // self loop (norm dis[c]*dis[c]; outer dis[c] applied at end)
        uint4 s0, s1;
        LOADROW(c, s0, s1);
        float ds = MODE ? dis[c] : 1.0f;
        ACCUMS(s0, s1, ds);
    }

    int2 be = node_be[c];
    int end = be.y;
    int j = be.x + g;
    if (j < end) {
        int r_cur = sorted_row[j];
        uint4 c0, c1;
        LOADROW(r_cur, c0, c1);
        float d_cur = MODE ? dis[r_cur] : 1.0f;
        int j1 = j + 8;
        int r_nxt = (j1 < end) ? sorted_row[j1] : 0;
        while (j1 < end) {
            int j2 = j1 + 8;
            int r_nn = (j2 < end) ? sorted_row[j2] : 0;  // idx 2 ahead
            uint4 n0, n1;
            LOADROW(r_nxt, n0, n1);                      // row 1 ahead
            float d_nxt = MODE ? dis[r_nxt] : 1.0f;
            ACCUMS(c0, c1, d_cur);                       // current from regs
            c0 = n0; c1 = n1; d_cur = d_nxt;
            r_nxt = r_nn;
            j1 = j2;
        }
        ACCUMS(c0, c1, d_cur);
    }
#undef LOADROW
#undef ACCUMS

#pragma unroll
    for (int k = 0; k < 16; ++k) {
        acc[k] += __shfl_xor(acc[k], 8);
        acc[k] += __shfl_xor(acc[k], 16);
        acc[k] += __shfl_xor(acc[k], 32);
    }

    if (g == 0) {
        float ds = dis[c];
        const float4* b4 = (const float4*)b;
        float4* op = (float4*)(out + (size_t)c * D + l8 * 16);
#pragma unroll
        for (int q = 0; q < 4; ++q) {
            float4 bb = b4[l8 * 4 + q];
            float4 o;
            o.x = fmaf(ds, acc[q * 4 + 0], bb.x);
            o.y = fmaf(ds, acc[q * 4 + 1], bb.y);
            o.z = fmaf(ds, acc[q * 4 + 2], bb.z);
            o.w = fmaf(ds, acc[q * 4 + 3], bb.w);
            if (MODE) {
                o.x = fmaxf(o.x, 0.f); o.y = fmaxf(o.y, 0.f);
                o.z = fmaxf(o.z, 0.f); o.w = fmaxf(o.w, 0.f);
            }
            op[q] = o;
        }
    }
}

// ---------------------------------------------------------------- launch
extern "C" void kernel_launch(void* const* d_in, const int* in_sizes, int n_in,
                              void* d_out, int out_size, void* d_ws, size_t ws_size,
                              hipStream_t stream) {
    const float* x  = (const float*)d_in[0];
    const int*   ei = (const int*)d_in[1];
    const float* W1 = (const float*)d_in[2];
    const float* b1 = (const float*)d_in[3];
    const float* W2 = (const float*)d_in[4];
    const float* b2 = (const float*)d_in[5];

    float* out = (float*)d_out;
    float* x2 = out;                        // tuple elem 0
    float* x1 = out + (size_t)N_NODES * D;  // tuple elem 1

    const int4* row4 = (const int4*)ei;                 // edge_index[0]
    const int4* col4 = (const int4*)(ei + N_EDGES);     // edge_index[1]

    // workspace layout (all regions 16B-aligned)
    char* w = (char*)d_ws;
    unsigned short* cnt_bb = (unsigned short*)w;            w += 157 * 128 * 2;   // 40192
    float* dis             = (float*)w;                     w += 10016 * 4;       // 40064
    int2* node_be          = (int2*)w;                      w += 10016 * 8;       // 80128
    unsigned int* bucketed = (unsigned int*)w;              w += (size_t)NBUCK * SLOTS * 4;  // 6.28MB
    int* sorted_row        = (int*)w;                       w += (size_t)NBUCK * CAP * 4;    // 2.89MB
    unsigned int* h        = (unsigned int*)w;              // 640000 u32 = 2.56MB

    k_bucket<<<BWG, 256, 0, stream>>>(row4, col4, cnt_bb, bucketed);
    k_fused1<<<NBUCK + 626, 256, 0, stream>>>(bucketed, cnt_bb, sorted_row, node_be, dis,
                                              x, W1, (uint2*)h);
    k_gather<1><<<N_NODES / 4, 256, 0, stream>>>((const uint4*)h, node_be, sorted_row, dis, b1, x1);
    k_gemm2<<<626, 256, 0, stream>>>(x1, W2, dis, (uint2*)h);
    k_gather<0><<<N_NODES / 4, 256, 0, stream>>>((const uint4*)h, node_be, sorted_row, dis, b2, x2);
}